// Round 3
// baseline (468.087 us; speedup 1.0000x reference)
//
#include <hip/hip_runtime.h>
#include <hip/hip_bf16.h>

namespace {

constexpr int B_ = 16;
constexpr int T_ = 32;
constexpr int N_ = 6000;
constexpr int K_ = 32;
constexpr int D_ = 8;
constexpr float EPS_ = 1e-8f;
constexpr float PW_  = 0.1f;

constexpr int CH = 256;                  // n-chunk per block
constexpr int NB = (N_ + CH - 1) / CH;   // 24

// workspace layout (float offsets)
constexpr int FTY_OFF = 0;                         // B*T*K*D = 131072
constexpr int SYY_OFF = FTY_OFF + B_*T_*K_*D_;     // B*T*D = 4096
constexpr int SY_OFF  = SYY_OFF + B_*T_*D_;        // B*T*D
constexpr int FTF_OFF = SY_OFF  + B_*T_*D_;        // B*K*K = 16384
constexpr int SP_OFF  = FTF_OFF + B_*K_*K_;        // B*K = 512
constexpr int ZERO_FLOATS = SP_OFF + B_*K_;        // accumulators needing zero-init
constexpr int INV_OFF = ZERO_FLOATS;               // B*K*K (fully overwritten)

// ---------------------------------------------------------------------------
// Main streaming kernel: one pass over y_ts computing Fty[b,t,k,d], Syy[b,t,d],
// Sy[b,t,d]; plus FtF[b,k,j] and Sp[b,k] from the LDS-staged preds chunk.
// Grid: B*NB blocks x 512 threads. Lane map: k = lane&31, nsub = lane>>5.
// ---------------------------------------------------------------------------
__global__ __launch_bounds__(512)
void stats_kernel(const float* __restrict__ preds,
                  const float* __restrict__ y,
                  float* __restrict__ ws)
{
  __shared__ float p_lds[CH * K_];     // 32 KB, [n][k]
  __shared__ float red[8 * K_ * 9];    // 9216 B  cross-wave reduce (pad 9)
  __shared__ float red2[8 * 32];       // 1 KB

  const int tid  = threadIdx.x;
  const int w    = tid >> 6;
  const int lane = tid & 63;
  const int k    = lane & 31;
  const int nsub = lane >> 5;

  const int bb = blockIdx.x / NB;
  const int c  = blockIdx.x - bb * NB;
  const int n0 = c * CH;
  const bool full = (n0 + CH) <= N_;

  // ---- stage preds chunk into LDS (zero-pad past N) ----
  const float* pb = preds + (size_t)bb * N_ * K_ + (size_t)n0 * K_;
  #pragma unroll
  for (int i = 0; i < 4; ++i) {
    const int idx = i * 512 + tid;   // float4 index in chunk
    const int off = idx * 4;
    float4 v = make_float4(0.f, 0.f, 0.f, 0.f);
    if (full || (n0 + (off >> 5)) < N_)
      v = *reinterpret_cast<const float4*>(pb + off);
    *reinterpret_cast<float4*>(p_lds + off) = v;
  }
  __syncthreads();

  // ---- FtF + Sp partials (once per block) ----
  {
    float a2[K_];
    #pragma unroll
    for (int j = 0; j < K_; ++j) a2[j] = 0.f;
    float sp = 0.f;
    for (int it = 0; it < CH/16; ++it) {
      const int nloc = it*16 + w*2 + nsub;
      const float pk = p_lds[nloc*K_ + k];
      sp += pk;
      const float4* row = reinterpret_cast<const float4*>(p_lds + nloc*K_);
      #pragma unroll
      for (int j4 = 0; j4 < 8; ++j4) {
        const float4 r = row[j4];
        a2[j4*4+0] = fmaf(pk, r.x, a2[j4*4+0]);
        a2[j4*4+1] = fmaf(pk, r.y, a2[j4*4+1]);
        a2[j4*4+2] = fmaf(pk, r.z, a2[j4*4+2]);
        a2[j4*4+3] = fmaf(pk, r.w, a2[j4*4+3]);
      }
    }
    #pragma unroll
    for (int j = 0; j < K_; ++j) a2[j] += __shfl_down(a2[j], 32);
    sp += __shfl_down(sp, 32);

    float* ftf = ws + FTF_OFF + bb * (K_*K_);
    #pragma unroll
    for (int g = 0; g < 4; ++g) {
      if (lane < 32) {
        #pragma unroll
        for (int j = 0; j < 8; ++j) red[w*288 + k*9 + j] = a2[g*8 + j];
      }
      __syncthreads();
      if (tid < 256) {
        const int kk = tid >> 3, jj = tid & 7;
        float s = 0.f;
        #pragma unroll
        for (int ww = 0; ww < 8; ++ww) s += red[ww*288 + kk*9 + jj];
        atomicAdd(&ftf[kk*K_ + g*8 + jj], s);
      }
      __syncthreads();
    }
    if (lane < 32) red2[w*32 + k] = sp;
    __syncthreads();
    if (tid < 32) {
      float s = 0.f;
      #pragma unroll
      for (int ww = 0; ww < 8; ++ww) s += red2[ww*32 + tid];
      atomicAdd(&ws[SP_OFF + bb*K_ + tid], s);
    }
    __syncthreads();
  }

  // ---- per-t streaming pass: Fty, Syy, Sy ----
  const int dly = lane & 7;       // mini-pass d
  const int q   = lane >> 3;      // 0..7
  const int itq = q >> 1;         // 0..3
  const int rq  = q & 1;

  for (int t = 0; t < T_; ++t) {
    const float* yrow = y + (((size_t)bb*T_ + t) * N_ + n0) * D_;
    float acc[D_];
    #pragma unroll
    for (int d = 0; d < D_; ++d) acc[d] = 0.f;

    if (full) {
      #pragma unroll 2
      for (int it = 0; it < 16; ++it) {
        const int nloc = it*16 + w*2 + nsub;
        const float pk = p_lds[nloc*K_ + k];
        const float4* yp = reinterpret_cast<const float4*>(yrow + nloc*D_);
        const float4 y0 = yp[0];
        const float4 y1 = yp[1];
        acc[0] = fmaf(pk, y0.x, acc[0]);
        acc[1] = fmaf(pk, y0.y, acc[1]);
        acc[2] = fmaf(pk, y0.z, acc[2]);
        acc[3] = fmaf(pk, y0.w, acc[3]);
        acc[4] = fmaf(pk, y1.x, acc[4]);
        acc[5] = fmaf(pk, y1.y, acc[5]);
        acc[6] = fmaf(pk, y1.z, acc[6]);
        acc[7] = fmaf(pk, y1.w, acc[7]);
      }
    } else {
      for (int it = 0; it < 16; ++it) {
        const int nloc = it*16 + w*2 + nsub;
        const float pk = p_lds[nloc*K_ + k];
        float4 y0 = make_float4(0.f,0.f,0.f,0.f), y1 = y0;
        if ((n0 + nloc) < N_) {
          const float4* yp = reinterpret_cast<const float4*>(yrow + nloc*D_);
          y0 = yp[0]; y1 = yp[1];
        }
        acc[0] = fmaf(pk, y0.x, acc[0]);
        acc[1] = fmaf(pk, y0.y, acc[1]);
        acc[2] = fmaf(pk, y0.z, acc[2]);
        acc[3] = fmaf(pk, y0.w, acc[3]);
        acc[4] = fmaf(pk, y1.x, acc[4]);
        acc[5] = fmaf(pk, y1.y, acc[5]);
        acc[6] = fmaf(pk, y1.z, acc[6]);
        acc[7] = fmaf(pk, y1.w, acc[7]);
      }
    }

    // Syy / Sy mini-pass (L1-hot re-read; each (row,d) exactly once per wave)
    float syy = 0.f, sy = 0.f;
    #pragma unroll
    for (int j2 = 0; j2 < 4; ++j2) {
      const int it   = j2*4 + itq;
      const int nloc = it*16 + w*2 + rq;
      float v = 0.f;
      if (full || (n0 + nloc) < N_) v = yrow[nloc*D_ + dly];
      syy = fmaf(v, v, syy);
      sy += v;
    }

    #pragma unroll
    for (int d = 0; d < D_; ++d) acc[d] += __shfl_down(acc[d], 32);
    syy += __shfl_down(syy, 32);  sy += __shfl_down(sy, 32);
    syy += __shfl_down(syy, 16);  sy += __shfl_down(sy, 16);
    syy += __shfl_down(syy, 8);   sy += __shfl_down(sy, 8);

    if (lane < 32) {
      #pragma unroll
      for (int d = 0; d < D_; ++d) red[w*288 + k*9 + d] = acc[d];
    }
    if (lane < 8) { red2[w*32 + lane] = syy; red2[w*32 + 8 + lane] = sy; }
    __syncthreads();

    if (tid < 256) {
      const int kk = tid >> 3, dd = tid & 7;
      float s = 0.f;
      #pragma unroll
      for (int ww = 0; ww < 8; ++ww) s += red[ww*288 + kk*9 + dd];
      atomicAdd(&ws[FTY_OFF + ((size_t)(bb*T_ + t)*K_ + kk)*D_ + dd], s);
    } else if (tid < 272) {
      const int i2  = tid - 256;
      const int dd  = i2 & 7;
      const int sel = i2 >> 3;    // 0 = Syy, 1 = Sy
      float s = 0.f;
      #pragma unroll
      for (int ww = 0; ww < 8; ++ww) s += red2[ww*32 + sel*8 + dd];
      atomicAdd(&ws[(sel ? SY_OFF : SYY_OFF) + (bb*T_ + t)*D_ + dd], s);
    }
    __syncthreads();
  }
}

// ---------------------------------------------------------------------------
// Gauss-Jordan inverse of (FtF + EPS*I), 32x32 per batch. SPD and strongly
// diagonally dominant (diag ~6000, offdiag ~77) -> no pivoting needed.
// ---------------------------------------------------------------------------
__global__ __launch_bounds__(256)
void invert_kernel(float* __restrict__ ws)
{
  __shared__ float M[32][65];
  __shared__ float fcol[32];
  const int b = blockIdx.x;
  const int tid = threadIdx.x;
  const float* A = ws + FTF_OFF + b * (K_*K_);

  for (int idx = tid; idx < 32*64; idx += 256) {
    const int r = idx >> 6, c2 = idx & 63;
    float v;
    if (c2 < 32) v = A[r*32 + c2] + (r == c2 ? EPS_ : 0.f);
    else         v = ((c2 - 32) == r) ? 1.f : 0.f;
    M[r][c2] = v;
  }
  __syncthreads();

  for (int p = 0; p < 32; ++p) {
    const float inv_piv = 1.0f / M[p][p];
    __syncthreads();
    if (tid < 64) {
      M[p][tid] *= inv_piv;
    } else if (tid < 96) {
      const int r = tid - 64;
      fcol[r] = (r == p) ? 0.f : M[r][p];
    }
    __syncthreads();
    for (int idx = tid; idx < 32*64; idx += 256) {
      const int r = idx >> 6, c2 = idx & 63;
      if (r != p) M[r][c2] = fmaf(-fcol[r], M[p][c2], M[r][c2]);
    }
    __syncthreads();
  }

  for (int idx = tid; idx < 32*32; idx += 256) {
    const int r = idx >> 5, c2 = idx & 31;
    ws[INV_OFF + b*(K_*K_) + idx] = M[r][c2 + 32];
  }
}

// ---------------------------------------------------------------------------
// Finisher per (b,t): beta = inv*Fty, gamma = FtF*beta,
// ss_res[d] = Syy - sum_k (2*Fty - gamma)*beta; r2; decay; atomic into out.
// ---------------------------------------------------------------------------
__global__ __launch_bounds__(256)
void finish_kernel(const float* __restrict__ ws,
                   const float* __restrict__ imp,
                   float* __restrict__ out)
{
  const int bt = blockIdx.x;
  const int b  = bt / T_;
  const int t  = bt - b * T_;
  const int tid = threadIdx.x;

  __shared__ float sInv[32][33];
  __shared__ float sFtF[32][33];
  __shared__ float sFty[32*8];
  __shared__ float sBeta[32*8];
  __shared__ float sRed[32][8];
  __shared__ float sW[8];

  for (int idx = tid; idx < 1024; idx += 256) {
    const int r = idx >> 5, c2 = idx & 31;
    sInv[r][c2] = ws[INV_OFF + b*(K_*K_) + idx];
    sFtF[r][c2] = ws[FTF_OFF + b*(K_*K_) + idx];
  }
  sFty[tid] = ws[FTY_OFF + bt*(K_*D_) + tid];
  __syncthreads();

  const int kk = tid >> 3, dd = tid & 7;
  float beta = 0.f;
  #pragma unroll
  for (int j = 0; j < 32; ++j) beta = fmaf(sInv[kk][j], sFty[j*8 + dd], beta);
  sBeta[kk*8 + dd] = beta;
  __syncthreads();

  float gamma = 0.f;
  #pragma unroll
  for (int j = 0; j < 32; ++j) gamma = fmaf(sFtF[kk][j], sBeta[j*8 + dd], gamma);
  const float fty = sFty[kk*8 + dd];
  sRed[kk][dd] = (2.f*fty - gamma) * beta;
  __syncthreads();

  if (tid < 8) {
    const int d = tid;
    float dots = 0.f;
    #pragma unroll
    for (int k2 = 0; k2 < 32; ++k2) dots += sRed[k2][d];
    const float syy = ws[SYY_OFF + bt*D_ + d];
    const float syv = ws[SY_OFF  + bt*D_ + d];
    const float ss_res = syy - dots;
    const float ss_tot = syy - syv*syv*(1.0f/N_) + EPS_;
    const float r2 = 1.f - ss_res/ss_tot;
    sW[d] = r2 * imp[d];
  }
  __syncthreads();

  if (tid == 0) {
    float wr2 = 0.f;
    #pragma unroll
    for (int d = 0; d < 8; ++d) wr2 += sW[d];
    const float dec = powf(0.9f, (float)t);
    atomicAdd(out, -wr2 * dec * (1.0f / (T_ * B_)));
  }
}

// ---------------------------------------------------------------------------
// Correlation penalty per batch: cov = FtF - Sp Sp^T/N; corr off-diag sq-sum.
// ---------------------------------------------------------------------------
__global__ __launch_bounds__(256)
void corr_kernel(const float* __restrict__ ws, float* __restrict__ out)
{
  const int b = blockIdx.x;
  const int tid = threadIdx.x;
  __shared__ float sC[32][33];
  __shared__ float sStd[32];

  for (int idx = tid; idx < 1024; idx += 256) {
    const int r = idx >> 5, c2 = idx & 31;
    const float cov = ws[FTF_OFF + b*(K_*K_) + idx]
                    - ws[SP_OFF + b*K_ + r] * ws[SP_OFF + b*K_ + c2] * (1.0f/N_);
    sC[r][c2] = cov;
  }
  __syncthreads();
  if (tid < 32) sStd[tid] = sqrtf(sC[tid][tid]);
  __syncthreads();

  float acc = 0.f;
  for (int idx = tid; idx < 1024; idx += 256) {
    const int r = idx >> 5, c2 = idx & 31;
    if (r != c2) {
      const float cr = sC[r][c2] / (sStd[r] * sStd[c2]);
      acc = fmaf(cr, cr, acc);
    }
  }
  acc += __shfl_down(acc, 32);
  acc += __shfl_down(acc, 16);
  acc += __shfl_down(acc, 8);
  acc += __shfl_down(acc, 4);
  acc += __shfl_down(acc, 2);
  acc += __shfl_down(acc, 1);
  if ((tid & 63) == 0) atomicAdd(out, acc * (PW_ / B_));
}

} // namespace

extern "C" void kernel_launch(void* const* d_in, const int* in_sizes, int n_in,
                              void* d_out, int out_size, void* d_ws, size_t ws_size,
                              hipStream_t stream)
{
  const float* preds = (const float*)d_in[0];
  const float* y     = (const float*)d_in[1];
  const float* imp   = (const float*)d_in[2];
  float* out = (float*)d_out;
  float* ws  = (float*)d_ws;

  hipMemsetAsync(ws, 0, (size_t)ZERO_FLOATS * sizeof(float), stream);
  hipMemsetAsync(out, 0, sizeof(float), stream);

  stats_kernel<<<B_*NB, 512, 0, stream>>>(preds, y, ws);
  invert_kernel<<<B_, 256, 0, stream>>>(ws);
  finish_kernel<<<B_*T_, 256, 0, stream>>>(ws, imp, out);
  corr_kernel<<<B_, 256, 0, stream>>>(ws, out);
}

// Round 7
// 239.512 us; speedup vs baseline: 1.9543x; 1.9543x over previous
//
#include <hip/hip_runtime.h>

namespace {

constexpr int B_ = 16;
constexpr int T_ = 32;
constexpr int N_ = 6000;
constexpr int K_ = 32;
constexpr int D_ = 8;
constexpr float EPS_ = 1e-8f;
constexpr float PW_  = 0.1f;

constexpr int CH = 256;                  // n-chunk per block
constexpr int NB = 24;                   // ceil(6000/256)
constexpr int TS = 4;                    // t-splits per (b,chunk)
constexpr int TC = T_ / TS;              // 8 timesteps per block

// workspace layout (float offsets)
constexpr int FTY_OFF = 0;                         // B*T*K*D = 131072
constexpr int SYY_OFF = FTY_OFF + B_*T_*K_*D_;     // B*T*D
constexpr int SY_OFF  = SYY_OFF + B_*T_*D_;        // B*T*D
constexpr int FTF_OFF = SY_OFF  + B_*T_*D_;        // B*K*K
constexpr int SP_OFF  = FTF_OFF + B_*K_*K_;        // B*K
constexpr int ZERO_FLOATS = SP_OFF + B_*K_;
constexpr int INV_OFF = ZERO_FLOATS;               // B*K*K (fully overwritten)

// async global->LDS, 16B per lane. dst must be the WAVE-uniform base; HW adds lane*16.
__device__ inline void gload_lds16(const float* g, float* l) {
  __builtin_amdgcn_global_load_lds(
      (const __attribute__((address_space(1))) void*)g,
      (__attribute__((address_space(3))) void*)l, 16, 0, 0);
}

// ---------------------------------------------------------------------------
// stats: grid = B*NB*TS blocks x 512. Each block: one (b, n-chunk), TC t's.
// y staged per-t into LDS (global_load_lds, double-buffered); p chunk in LDS.
// Outputs via atomicAdd: Fty[b,t,k,d], Syy/Sy[b,t,d]; FtF/Sp by ts==0 blocks.
// ---------------------------------------------------------------------------
__global__ __launch_bounds__(512)
void stats_kernel(const float* __restrict__ preds,
                  const float* __restrict__ y,
                  float* __restrict__ ws)
{
  __shared__ float p_lds[CH * K_];       // 32 KB  [n][k]
  __shared__ float y_lds[2][CH * D_];    // 16 KB  [buf][n*8+d]
  __shared__ float red[2][8 * 288];      // 18 KB  [par][w*288 + k*9 + d]
  __shared__ float red2[2][8 * 16];      //  1 KB  [par][w*16 + sel*8 + d]

  const int tid  = threadIdx.x;
  const int w    = tid >> 6;
  const int lane = tid & 63;
  const int k    = lane & 31;
  const int nsub = lane >> 5;

  const int bid = blockIdx.x;
  const int ts  = bid & (TS - 1);
  const int c   = (bid >> 2) % NB;
  const int bb  = bid / (TS * NB);
  const int n0  = c * CH;
  const int rows_valid = min(CH, N_ - n0);
  const int t0  = ts * TC;

  // ---- stage preds chunk into LDS (async, zero-pad past N) ----
  const float* pb = preds + ((size_t)bb * N_ + n0) * K_;
  const int pvalid4 = rows_valid * 8;          // float4 count (rows*32/4)
  #pragma unroll
  for (int i = 0; i < 4; ++i) {
    const int idx = i * 512 + tid;             // float4 index in chunk
    if (idx < pvalid4) gload_lds16(pb + (size_t)idx * 4, p_lds + i * 2048 + w * 256);
    else *reinterpret_cast<float4*>(p_lds + idx * 4) = make_float4(0.f, 0.f, 0.f, 0.f);
  }

  // ---- issue y stage for t0 into buf 0 ----
  const int yvalid4 = rows_valid * 2;          // float4 count (rows*8/4)
  {
    const float* src = y + (((size_t)bb * T_ + t0) * N_ + n0) * D_;
    if (tid < yvalid4) gload_lds16(src + (size_t)tid * 4, &y_lds[0][w * 256]);
    else *reinterpret_cast<float4*>(&y_lds[0][tid * 4]) = make_float4(0.f, 0.f, 0.f, 0.f);
  }

  __syncthreads();   // p_lds and y_lds[0] ready (barrier drains vmcnt)

  // ---- FtF + Sp (ts==0 blocks only; block-uniform branch) ----
  if (ts == 0) {
    float a2[K_];
    #pragma unroll
    for (int j = 0; j < K_; ++j) a2[j] = 0.f;
    float sp = 0.f;
    for (int it = 0; it < CH / 16; ++it) {
      const int nloc = it * 16 + w * 2 + nsub;
      const float pk = p_lds[nloc * K_ + k];
      sp += pk;
      const float4* row = reinterpret_cast<const float4*>(p_lds + nloc * K_);
      #pragma unroll
      for (int j4 = 0; j4 < 8; ++j4) {
        const float4 r = row[j4];
        a2[j4*4+0] = fmaf(pk, r.x, a2[j4*4+0]);
        a2[j4*4+1] = fmaf(pk, r.y, a2[j4*4+1]);
        a2[j4*4+2] = fmaf(pk, r.z, a2[j4*4+2]);
        a2[j4*4+3] = fmaf(pk, r.w, a2[j4*4+3]);
      }
    }
    #pragma unroll
    for (int j = 0; j < K_; ++j) a2[j] += __shfl_down(a2[j], 32);
    sp += __shfl_down(sp, 32);

    float* ftf = ws + FTF_OFF + bb * (K_*K_);
    #pragma unroll
    for (int g = 0; g < 4; ++g) {
      if (lane < 32) {
        #pragma unroll
        for (int j = 0; j < 8; ++j) red[0][w*288 + k*9 + j] = a2[g*8 + j];
      }
      __syncthreads();
      if (tid < 256) {
        const int kk = tid >> 3, jj = tid & 7;
        float s = 0.f;
        #pragma unroll
        for (int ww = 0; ww < 8; ++ww) s += red[0][ww*288 + kk*9 + jj];
        atomicAdd(&ftf[kk*K_ + g*8 + jj], s);
      }
      __syncthreads();
    }
    if (lane < 32) red[0][w*288 + k*9] = sp;
    __syncthreads();
    if (tid < 32) {
      float s = 0.f;
      #pragma unroll
      for (int ww = 0; ww < 8; ++ww) s += red[0][ww*288 + tid*9];
      atomicAdd(&ws[SP_OFF + bb*K_ + tid], s);
    }
    __syncthreads();
  }

  // ---- per-t pass: Fty, Syy, Sy (y from LDS, double-buffered) ----
  const int dly = lane & 7;
  const int q   = lane >> 3;
  const int itq = q >> 1;
  const int rq  = q & 1;

  int cur = 0;
  for (int tt = 0; tt < TC; ++tt) {
    const int t = t0 + tt;

    // issue next-t stage into buf cur^1 (safe: last reads of cur^1 were at
    // t-1's compute, sealed by t-1's barrier)
    if (tt + 1 < TC) {
      const float* src = y + (((size_t)bb * T_ + (t + 1)) * N_ + n0) * D_;
      if (tid < yvalid4) gload_lds16(src + (size_t)tid * 4, &y_lds[cur ^ 1][w * 256]);
      else *reinterpret_cast<float4*>(&y_lds[cur ^ 1][tid * 4]) = make_float4(0.f, 0.f, 0.f, 0.f);
    }

    float acc[D_];
    #pragma unroll
    for (int d = 0; d < D_; ++d) acc[d] = 0.f;

    #pragma unroll 2
    for (int it = 0; it < 16; ++it) {
      const int nloc = it*16 + w*2 + nsub;
      const float pk = p_lds[nloc*K_ + k];
      const float4 y0 = *reinterpret_cast<const float4*>(&y_lds[cur][nloc*8]);
      const float4 y1 = *reinterpret_cast<const float4*>(&y_lds[cur][nloc*8 + 4]);
      acc[0] = fmaf(pk, y0.x, acc[0]);
      acc[1] = fmaf(pk, y0.y, acc[1]);
      acc[2] = fmaf(pk, y0.z, acc[2]);
      acc[3] = fmaf(pk, y0.w, acc[3]);
      acc[4] = fmaf(pk, y1.x, acc[4]);
      acc[5] = fmaf(pk, y1.y, acc[5]);
      acc[6] = fmaf(pk, y1.z, acc[6]);
      acc[7] = fmaf(pk, y1.w, acc[7]);
    }

    // Syy / Sy mini-pass: each (row,d) of the chunk exactly once per block
    float syy = 0.f, sy = 0.f;
    #pragma unroll
    for (int j2 = 0; j2 < 4; ++j2) {
      const int it   = j2*4 + itq;
      const int nloc = it*16 + w*2 + rq;
      const float v = y_lds[cur][nloc*8 + dly];
      syy = fmaf(v, v, syy);
      sy += v;
    }

    #pragma unroll
    for (int d = 0; d < D_; ++d) acc[d] += __shfl_down(acc[d], 32);
    syy += __shfl_down(syy, 32);  sy += __shfl_down(sy, 32);
    syy += __shfl_down(syy, 16);  sy += __shfl_down(sy, 16);
    syy += __shfl_down(syy, 8);   sy += __shfl_down(sy, 8);

    const int par = tt & 1;
    if (lane < 32) {
      #pragma unroll
      for (int d = 0; d < D_; ++d) red[par][w*288 + k*9 + d] = acc[d];
    }
    if (lane < 8) { red2[par][w*16 + lane] = syy; red2[par][w*16 + 8 + lane] = sy; }
    __syncthreads();   // seals red/red2 writes AND next-t stage drain

    if (tid < 256) {
      const int kk = tid >> 3, dd = tid & 7;
      float s = 0.f;
      #pragma unroll
      for (int ww = 0; ww < 8; ++ww) s += red[par][ww*288 + kk*9 + dd];
      atomicAdd(&ws[FTY_OFF + ((size_t)(bb*T_ + t)*K_ + kk)*D_ + dd], s);
    } else if (tid < 272) {
      const int i2  = tid - 256;
      const int dd  = i2 & 7;
      const int sel = i2 >> 3;    // 0 = Syy, 1 = Sy
      float s = 0.f;
      #pragma unroll
      for (int ww = 0; ww < 8; ++ww) s += red2[par][ww*16 + sel*8 + dd];
      atomicAdd(&ws[(sel ? SY_OFF : SYY_OFF) + (bb*T_ + t)*D_ + dd], s);
    }
    cur ^= 1;
  }
}

// ---------------------------------------------------------------------------
// Register-resident Gauss-Jordan inverse of (FtF + EPS*I), one 64-lane wave
// per batch; lane owns one column of [A | I]; zero barriers, zero LDS.
// SPD + strongly diagonally dominant (diag ~6000) -> no pivoting.
// ---------------------------------------------------------------------------
__global__ __launch_bounds__(64)
void invert_kernel(float* __restrict__ ws)
{
  const int b = blockIdx.x;
  const int lane = threadIdx.x;
  const float* A = ws + FTF_OFF + b * (K_*K_);

  float m[32];
  #pragma unroll
  for (int r = 0; r < 32; ++r) {
    if (lane < 32) m[r] = A[r*32 + lane] + (r == lane ? EPS_ : 0.f);
    else           m[r] = ((lane - 32) == r) ? 1.f : 0.f;
  }

  #pragma unroll
  for (int p = 0; p < 32; ++p) {
    const float ip = 1.0f / __shfl(m[p], p);
    m[p] *= ip;
    #pragma unroll
    for (int r = 0; r < 32; ++r) {
      if (r == p) continue;
      const float f = __shfl(m[r], p);
      m[r] = fmaf(-f, m[p], m[r]);
    }
  }

  float* out = ws + INV_OFF + b * (K_*K_);
  #pragma unroll
  for (int r = 0; r < 32; ++r)
    if (lane >= 32) out[r*32 + (lane - 32)] = m[r];
}

// ---------------------------------------------------------------------------
// finish per (b,t): beta = inv @ Fty;
// ss_res[d] = Syy - sum_k Fty*beta - EPS*|beta|^2  (exact identity, no gamma)
// ---------------------------------------------------------------------------
__global__ __launch_bounds__(256)
void finish_kernel(const float* __restrict__ ws,
                   const float* __restrict__ imp,
                   float* __restrict__ out)
{
  const int bt = blockIdx.x;
  const int b  = bt / T_;
  const int t  = bt - b * T_;
  const int tid = threadIdx.x;

  __shared__ float sInv[32][33];
  __shared__ float sFty[256];
  __shared__ float sRed[32][8];
  __shared__ float sW[8];

  for (int idx = tid; idx < 1024; idx += 256)
    sInv[idx >> 5][idx & 31] = ws[INV_OFF + b*(K_*K_) + idx];
  sFty[tid] = ws[FTY_OFF + (size_t)bt * 256 + tid];
  __syncthreads();

  const int kk = tid >> 3, dd = tid & 7;
  float beta = 0.f;
  #pragma unroll
  for (int j = 0; j < 32; ++j) beta = fmaf(sInv[kk][j], sFty[j*8 + dd], beta);
  const float fty = sFty[kk*8 + dd];
  sRed[kk][dd] = fty * beta + EPS_ * beta * beta;
  __syncthreads();

  if (tid < 8) {
    float dots = 0.f;
    #pragma unroll
    for (int k2 = 0; k2 < 32; ++k2) dots += sRed[k2][tid];
    const float syy = ws[SYY_OFF + bt*D_ + tid];
    const float syv = ws[SY_OFF  + bt*D_ + tid];
    const float ss_res = syy - dots;
    const float ss_tot = syy - syv*syv*(1.0f/N_) + EPS_;
    sW[tid] = (1.f - ss_res/ss_tot) * imp[tid];
  }
  __syncthreads();

  if (tid == 0) {
    float wr2 = 0.f;
    #pragma unroll
    for (int d = 0; d < 8; ++d) wr2 += sW[d];
    atomicAdd(out, -wr2 * powf(0.9f, (float)t) * (1.0f / (T_ * B_)));
  }
}

// ---------------------------------------------------------------------------
// Correlation penalty per batch.
// ---------------------------------------------------------------------------
__global__ __launch_bounds__(256)
void corr_kernel(const float* __restrict__ ws, float* __restrict__ out)
{
  const int b = blockIdx.x;
  const int tid = threadIdx.x;
  __shared__ float sC[32][33];
  __shared__ float sStd[32];

  for (int idx = tid; idx < 1024; idx += 256) {
    const int r = idx >> 5, c2 = idx & 31;
    const float cov = ws[FTF_OFF + b*(K_*K_) + idx]
                    - ws[SP_OFF + b*K_ + r] * ws[SP_OFF + b*K_ + c2] * (1.0f/N_);
    sC[r][c2] = cov;
  }
  __syncthreads();
  if (tid < 32) sStd[tid] = sqrtf(sC[tid][tid]);
  __syncthreads();

  float acc = 0.f;
  for (int idx = tid; idx < 1024; idx += 256) {
    const int r = idx >> 5, c2 = idx & 31;
    if (r != c2) {
      const float cr = sC[r][c2] / (sStd[r] * sStd[c2]);
      acc = fmaf(cr, cr, acc);
    }
  }
  acc += __shfl_down(acc, 32);
  acc += __shfl_down(acc, 16);
  acc += __shfl_down(acc, 8);
  acc += __shfl_down(acc, 4);
  acc += __shfl_down(acc, 2);
  acc += __shfl_down(acc, 1);
  if ((tid & 63) == 0) atomicAdd(out, acc * (PW_ / B_));
}

} // namespace

extern "C" void kernel_launch(void* const* d_in, const int* in_sizes, int n_in,
                              void* d_out, int out_size, void* d_ws, size_t ws_size,
                              hipStream_t stream)
{
  const float* preds = (const float*)d_in[0];
  const float* y     = (const float*)d_in[1];
  const float* imp   = (const float*)d_in[2];
  float* out = (float*)d_out;
  float* ws  = (float*)d_ws;

  hipMemsetAsync(ws, 0, (size_t)ZERO_FLOATS * sizeof(float), stream);
  hipMemsetAsync(out, 0, sizeof(float), stream);

  stats_kernel<<<B_ * NB * TS, 512, 0, stream>>>(preds, y, ws);
  invert_kernel<<<B_, 64, 0, stream>>>(ws);
  finish_kernel<<<B_ * T_, 256, 0, stream>>>(ws, imp, out);
  corr_kernel<<<B_, 256, 0, stream>>>(ws, out);
}